// Round 1
// baseline (747.688 us; speedup 1.0000x reference)
//
#include <hip/hip_runtime.h>

#define NPTS   65536      // 16 * 64 * 64 points
#define DIM    64         // embedding dim
#define KCODES 1024       // codebook entries
#define CHUNK  256        // codes staged in LDS per pass
#define HW     4096       // 64*64 spatial positions per (b, d) plane

// Prep: per-code squared norms into d_ws, and zero the loss accumulator
// (d_out is re-poisoned to 0xAA before every launch, so we must zero it here).
__global__ void vq_prep_kernel(const float* __restrict__ cb,
                               float* __restrict__ cbn,
                               float* __restrict__ loss_ptr) {
    int k = blockIdx.x * blockDim.x + threadIdx.x;
    if (k == 0) *loss_ptr = 0.0f;
    if (k < KCODES) {
        const float* row = cb + (size_t)k * DIM;
        float s = 0.0f;
        #pragma unroll
        for (int d = 0; d < DIM; ++d) s = fmaf(row[d], row[d], s);
        cbn[k] = s;
    }
}

__global__ __launch_bounds__(256, 1) void vq_main_kernel(
    const float* __restrict__ x, const float* __restrict__ cb,
    const float* __restrict__ cbn, float* __restrict__ out,
    float* __restrict__ loss_ptr)
{
    __shared__ __align__(16) float s_cb[CHUNK * DIM];  // 64 KiB
    __shared__ float s_cbn[CHUNK];
    __shared__ float s_red[4];

    const int tid = threadIdx.x;
    const int n   = blockIdx.x * 256 + tid;     // point id
    const int b   = n >> 12;                     // batch (4096 points per image)
    const int hw  = n & 4095;                    // spatial position
    const float* xp = x + (size_t)b * (DIM * HW) + hw;

    // Load this point's 64 features (stride HW -> coalesced across lanes)
    float xv[DIM];
    float xnorm = 0.0f;
    #pragma unroll
    for (int d = 0; d < DIM; ++d) {
        float v = xp[(size_t)d * HW];
        xv[d] = v;
        xnorm = fmaf(v, v, xnorm);
    }

    float best = 3.4e38f;
    int   bidx = 0;

    for (int c0 = 0; c0 < KCODES; c0 += CHUNK) {
        __syncthreads();  // protect LDS reuse across chunks
        // Coalesced copy of 256 codes (4096 float4) into LDS
        const float4* src = (const float4*)(cb + (size_t)c0 * DIM);
        float4*       dst = (float4*)s_cb;
        #pragma unroll
        for (int i = 0; i < 16; ++i)
            dst[tid + 256 * i] = src[tid + 256 * i];
        s_cbn[tid] = cbn[c0 + tid];
        __syncthreads();

        #pragma unroll 2
        for (int k = 0; k < CHUNK; ++k) {
            const float4* cr = (const float4*)(s_cb + k * DIM);
            // 4 independent FMA chains for ILP; cb row read is a wave-broadcast
            float a0 = 0.f, a1 = 0.f, a2 = 0.f, a3 = 0.f;
            #pragma unroll
            for (int j = 0; j < 16; ++j) {
                float4 cv = cr[j];
                a0 = fmaf(cv.x, xv[4*j+0], a0);
                a1 = fmaf(cv.y, xv[4*j+1], a1);
                a2 = fmaf(cv.z, xv[4*j+2], a2);
                a3 = fmaf(cv.w, xv[4*j+3], a3);
            }
            // score = ||c||^2 - 2*x.c ; argmin matches distance argmin
            float score = s_cbn[k] - 2.0f * ((a0 + a1) + (a2 + a3));
            if (score < best) { best = score; bidx = c0 + k; }  // first-min wins
        }
    }

    // Gather winning code row (codebook is 256 KB -> L2-hot) and write NCHW
    const float* crow = cb + (size_t)bidx * DIM;
    float* op = out + (size_t)b * (DIM * HW) + hw;
    #pragma unroll
    for (int d = 0; d < DIM; ++d)
        op[(size_t)d * HW] = crow[d];

    // loss contribution: ||x - c_best||^2 = best_score + ||x||^2
    float contrib = best + xnorm;
    #pragma unroll
    for (int off = 32; off > 0; off >>= 1)
        contrib += __shfl_down(contrib, off, 64);
    const int wave = tid >> 6;
    if ((tid & 63) == 0) s_red[wave] = contrib;
    __syncthreads();
    if (tid == 0) {
        float s = (s_red[0] + s_red[1]) + (s_red[2] + s_red[3]);
        atomicAdd(loss_ptr, s * (1.25f / (float)(NPTS * DIM)));
    }
}

extern "C" void kernel_launch(void* const* d_in, const int* in_sizes, int n_in,
                              void* d_out, int out_size, void* d_ws, size_t ws_size,
                              hipStream_t stream) {
    const float* x  = (const float*)d_in[0];   // [16,64,64,64] NCHW fp32
    const float* cb = (const float*)d_in[1];   // [1024,64] fp32
    float* out      = (float*)d_out;           // quantized (4194304) + loss (1)
    float* cbn      = (float*)d_ws;            // 1024 floats scratch
    float* loss_ptr = out + (size_t)NPTS * DIM;

    vq_prep_kernel<<<4, 256, 0, stream>>>(cb, cbn, loss_ptr);
    vq_main_kernel<<<NPTS / 256, 256, 0, stream>>>(x, cb, cbn, out, loss_ptr);
}

// Round 2
// 97.589 us; speedup vs baseline: 7.6616x; 7.6616x over previous
//
#include <hip/hip_runtime.h>

#define NPTS   65536
#define DIM    64
#define KCODES 1024
#define HW     4096
#define ROWP   68          // padded LDS row stride (bf16 elems): 136 B, 8B-aligned, bank-spread

typedef __attribute__((ext_vector_type(8))) short  short8;
typedef __attribute__((ext_vector_type(4))) float  floatx4;
typedef __attribute__((ext_vector_type(2))) unsigned long long ull2;

__device__ __forceinline__ short f2bf(float f) {   // RNE fp32 -> bf16
    unsigned u = __builtin_bit_cast(unsigned, f);
    u = (u + 0x7FFFu + ((u >> 16) & 1u)) >> 16;
    return (short)u;
}
__device__ __forceinline__ float bf2f(short s) {
    unsigned u = ((unsigned)(unsigned short)s) << 16;
    return __builtin_bit_cast(float, u);
}

// Prep: cbn_nh[k] = -0.5*||c_k||^2 (fp32), and zero the loss slot (out is re-poisoned).
__global__ void vq_prep(const float* __restrict__ cb, float* __restrict__ cbn_nh,
                        float* __restrict__ loss_ptr) {
    int k = blockIdx.x * blockDim.x + threadIdx.x;
    if (k == 0) *loss_ptr = 0.0f;
    if (k < KCODES) {
        const float* row = cb + (size_t)k * DIM;
        float s = 0.0f;
        #pragma unroll
        for (int d = 0; d < DIM; ++d) s = fmaf(row[d], row[d], s);
        cbn_nh[k] = -0.5f * s;
    }
}

__global__ __launch_bounds__(256, 1) void vq_main(
    const float* __restrict__ x, const float* __restrict__ cb,
    const float* __restrict__ cbn_nh, float* __restrict__ out,
    float* __restrict__ loss_ptr)
{
    __shared__ __align__(16) short s_cb[KCODES * ROWP];   // 136 KB bf16 codebook
    __shared__ float s_cbn[KCODES];                        // 4 KB  (-0.5*||c||^2)
    __shared__ int   s_idx[256];
    __shared__ float s_red[4];

    const int tid  = threadIdx.x;
    const int lane = tid & 63;
    const int wave = tid >> 6;
    const int col  = lane & 15;   // MFMA n / C-col
    const int quad = lane >> 4;   // MFMA k-group / C-row-group

    // ---- stage codebook -> LDS bf16 (padded rows); coalesced float4 reads ----
    {
        const float4* src = (const float4*)cb;
        for (int i = 0; i < 64; ++i) {
            int f4 = tid + 256 * i;
            float4 v = src[f4];
            int e = f4 << 2;                 // element index; 4 elems stay in one code row
            int code = e >> 6, within = e & 63;
            unsigned long long p =
                ((unsigned long long)(unsigned short)f2bf(v.x)) |
                ((unsigned long long)(unsigned short)f2bf(v.y) << 16) |
                ((unsigned long long)(unsigned short)f2bf(v.z) << 32) |
                ((unsigned long long)(unsigned short)f2bf(v.w) << 48);
            *(unsigned long long*)&s_cb[code * ROWP + within] = p;
        }
        #pragma unroll
        for (int i = 0; i < 4; ++i) s_cbn[tid + 256 * i] = cbn_nh[tid + 256 * i];
    }

    // ---- A fragments: 64 points/wave, 4 row-blocks x 2 k-halves ----
    // A[m = lane&15][k = quad*8 + j]; x is NCHW so feature d of point n is at b*2^18 + d*4096 + hw
    const int p0 = blockIdx.x * 256 + wave * 64;
    short8 afrag[4][2];
    #pragma unroll
    for (int blk = 0; blk < 4; ++blk) {
        int n = p0 + blk * 16 + col;
        const float* bp = x + ((size_t)(n >> 12) << 18) + (n & 4095);
        #pragma unroll
        for (int kh = 0; kh < 2; ++kh) {
            int dbase = kh * 32 + quad * 8;
            short8 f;
            #pragma unroll
            for (int j = 0; j < 8; ++j)
                f[j] = f2bf(bp[(size_t)(dbase + j) * HW]);
            afrag[blk][kh] = f;
        }
    }
    __syncthreads();

    // ---- main loop: 64 tiles of 16 codes; argmax of (x.c - 0.5||c||^2) with idx packed ----
    float best[4][4];
    #pragma unroll
    for (int blk = 0; blk < 4; ++blk)
        #pragma unroll
        for (int r = 0; r < 4; ++r) best[blk][r] = -3.4e38f;

    for (int t = 0; t < 64; ++t) {
        const int cbase = t * 16;
        const int code  = cbase + col;
        const float initv = s_cbn[code];
        const unsigned idxv = (unsigned)code;
        // B frags: lane holds code n=col's k-slice; 8B loads (136B rows keep 8B align)
        const short* rp = &s_cb[code * ROWP + quad * 8];
        ull2 u0; u0.x = *(const unsigned long long*)rp;
        u0.y = *(const unsigned long long*)(rp + 4);
        ull2 u1; u1.x = *(const unsigned long long*)(rp + 32);
        u1.y = *(const unsigned long long*)(rp + 36);
        const short8 b0 = __builtin_bit_cast(short8, u0);
        const short8 b1 = __builtin_bit_cast(short8, u1);
        floatx4 cinit = {initv, initv, initv, initv};
        #pragma unroll
        for (int blk = 0; blk < 4; ++blk) {
            floatx4 acc = __builtin_amdgcn_mfma_f32_16x16x32_bf16(afrag[blk][0], b0, cinit, 0, 0, 0);
            acc = __builtin_amdgcn_mfma_f32_16x16x32_bf16(afrag[blk][1], b1, acc, 0, 0, 0);
            #pragma unroll
            for (int r = 0; r < 4; ++r) {
                unsigned pb = (__builtin_bit_cast(unsigned, acc[r]) & 0xFFFFFC00u) | idxv;
                best[blk][r] = fmaxf(best[blk][r], __builtin_bit_cast(float, pb));
            }
        }
    }

    // ---- reduce argmax across the 16 lanes sharing each C-row ----
    #pragma unroll
    for (int blk = 0; blk < 4; ++blk)
        #pragma unroll
        for (int r = 0; r < 4; ++r) {
            float v = best[blk][r];
            v = fmaxf(v, __shfl_xor(v, 1, 64));
            v = fmaxf(v, __shfl_xor(v, 2, 64));
            v = fmaxf(v, __shfl_xor(v, 4, 64));
            v = fmaxf(v, __shfl_xor(v, 8, 64));
            best[blk][r] = v;
        }
    // C/D row = quad*4 + r; one writer per 16-lane group
    if (col == 0) {
        #pragma unroll
        for (int blk = 0; blk < 4; ++blk)
            #pragma unroll
            for (int r = 0; r < 4; ++r)
                s_idx[wave * 64 + blk * 16 + quad * 4 + r] =
                    (int)(__builtin_bit_cast(unsigned, best[blk][r]) & 1023u);
    }
    // same-wave LDS write->read: ds ops are wave-ordered; compiler inserts lgkmcnt wait

    // ---- epilogue: lane i owns point p0+i. Gather bf16 code row from LDS,
    //      coalesced NCHW stores, exact fp32 loss vs re-read x (L2-hot). ----
    {
        int n = p0 + lane;
        int idx = s_idx[wave * 64 + lane];
        size_t base = ((size_t)(n >> 12) << 18) + (n & 4095);
        float* op = out + base;
        const float* xp = x + base;
        float lsum = 0.0f;
        #pragma unroll
        for (int j = 0; j < 16; ++j) {  // 4 bf16 per 8B LDS read
            unsigned long long u = *(const unsigned long long*)&s_cb[idx * ROWP + j * 4];
            #pragma unroll
            for (int e = 0; e < 4; ++e) {
                float c = bf2f((short)(u >> (16 * e)));
                int d = j * 4 + e;
                float xv = xp[(size_t)d * HW];
                op[(size_t)d * HW] = c;
                float diff = xv - c;
                lsum = fmaf(diff, diff, lsum);
            }
        }
        #pragma unroll
        for (int off = 32; off > 0; off >>= 1)
            lsum += __shfl_down(lsum, off, 64);
        if (lane == 0) s_red[wave] = lsum;
    }
    __syncthreads();
    if (tid == 0) {
        float s = (s_red[0] + s_red[1]) + (s_red[2] + s_red[3]);
        atomicAdd(loss_ptr, s * (1.25f / (float)((size_t)NPTS * DIM)));
    }
}

extern "C" void kernel_launch(void* const* d_in, const int* in_sizes, int n_in,
                              void* d_out, int out_size, void* d_ws, size_t ws_size,
                              hipStream_t stream) {
    const float* x  = (const float*)d_in[0];   // [16,64,64,64] NCHW fp32
    const float* cb = (const float*)d_in[1];   // [1024,64] fp32
    float* out      = (float*)d_out;           // quantized (4194304) + loss (1)
    float* cbn      = (float*)d_ws;            // 4 KB scratch
    float* loss_ptr = out + (size_t)NPTS * DIM;

    vq_prep<<<KCODES / 256, 256, 0, stream>>>(cb, cbn, loss_ptr);
    vq_main<<<NPTS / 256, 256, 0, stream>>>(x, cb, cbn, out, loss_ptr);
}

// Round 3
// 92.830 us; speedup vs baseline: 8.0544x; 1.0513x over previous
//
#include <hip/hip_runtime.h>

#define NPTS   65536
#define DIM    64
#define KCODES 1024
#define HW     4096
#define ROWP   68          // padded LDS row stride (bf16 elems): 136 B, 8B-aligned

typedef __attribute__((ext_vector_type(8))) short  short8;
typedef __attribute__((ext_vector_type(4))) float  floatx4;
typedef __attribute__((ext_vector_type(2))) unsigned long long ull2;

__device__ __forceinline__ short f2bf(float f) {   // RNE fp32 -> bf16
    unsigned u = __builtin_bit_cast(unsigned, f);
    u = (u + 0x7FFFu + ((u >> 16) & 1u)) >> 16;
    return (short)u;
}
__device__ __forceinline__ float bf2f(short s) {
    unsigned u = ((unsigned)(unsigned short)s) << 16;
    return __builtin_bit_cast(float, u);
}

// Tiny prep: zero the loss slot (d_out is re-poisoned to 0xAA before every launch).
__global__ void vq_zero(float* __restrict__ loss_ptr) {
    if (threadIdx.x == 0) *loss_ptr = 0.0f;
}

__global__ __launch_bounds__(1024, 4) void vq_main(
    const float* __restrict__ x, const float* __restrict__ cb,
    float* __restrict__ out, float* __restrict__ loss_ptr)
{
    __shared__ __align__(16) short s_cb[KCODES * ROWP];   // 136 KB bf16 codebook
    __shared__ float s_cbn[KCODES];                        // 4 KB (-0.5*||c_bf||^2)
    __shared__ int   s_idx[256];
    __shared__ float s_red[16];

    const int tid  = threadIdx.x;
    const int lane = tid & 63;
    const int wave = tid >> 6;
    const int col  = lane & 15;   // MFMA m/n index
    const int quad = lane >> 4;   // MFMA k-group / C-row-group

    // ---- stage codebook -> LDS bf16 + fused norms ----
    // f4 = tid + 1024*i covers all 16384 float4; code = f4>>4 is constant over
    // each aligned 16-lane group -> shuffle-reduce the norm partials in-register.
    {
        const float4* src = (const float4*)cb;
        #pragma unroll
        for (int i = 0; i < 16; ++i) {
            int f4 = tid + 1024 * i;
            float4 v = src[f4];
            short hx = f2bf(v.x), hy = f2bf(v.y), hz = f2bf(v.z), hw_ = f2bf(v.w);
            unsigned long long p =
                ((unsigned long long)(unsigned short)hx) |
                ((unsigned long long)(unsigned short)hy << 16) |
                ((unsigned long long)(unsigned short)hz << 32) |
                ((unsigned long long)(unsigned short)hw_ << 48);
            int code = f4 >> 4, w = f4 & 15;
            *(unsigned long long*)&s_cb[code * ROWP + w * 4] = p;
            float cx = bf2f(hx), cy = bf2f(hy), cz = bf2f(hz), cw = bf2f(hw_);
            float ns = fmaf(cx, cx, fmaf(cy, cy, fmaf(cz, cz, cw * cw)));
            ns += __shfl_xor(ns, 1, 64);
            ns += __shfl_xor(ns, 2, 64);
            ns += __shfl_xor(ns, 4, 64);
            ns += __shfl_xor(ns, 8, 64);
            if ((tid & 15) == 0) s_cbn[code] = -0.5f * ns;
        }
    }

    // ---- A fragments: wave owns 16 points; A[m=col][k=quad*8+j] ----
    const int p0  = blockIdx.x * 256;
    const int myn = p0 + wave * 16 + col;
    const float* bp = x + ((size_t)(myn >> 12) << 18) + (myn & 4095);
    short8 afrag[2];
    #pragma unroll
    for (int kh = 0; kh < 2; ++kh) {
        int dbase = kh * 32 + quad * 8;
        short8 f;
        #pragma unroll
        for (int j = 0; j < 8; ++j)
            f[j] = f2bf(bp[(size_t)(dbase + j) * HW]);
        afrag[kh] = f;
    }
    __syncthreads();

    // ---- main loop: 64 tiles of 16 codes; argmax of (x.c - 0.5||c||^2),
    //      code index packed into low 10 mantissa bits ----
    float best[4] = {-3.4e38f, -3.4e38f, -3.4e38f, -3.4e38f};
    for (int t = 0; t < 64; ++t) {
        const int code = t * 16 + col;
        const float initv = s_cbn[code];
        const unsigned idxv = (unsigned)code;
        const short* rp = &s_cb[code * ROWP + quad * 8];
        ull2 u0; u0.x = *(const unsigned long long*)rp;
        u0.y = *(const unsigned long long*)(rp + 4);
        ull2 u1; u1.x = *(const unsigned long long*)(rp + 32);
        u1.y = *(const unsigned long long*)(rp + 36);
        const short8 b0 = __builtin_bit_cast(short8, u0);
        const short8 b1 = __builtin_bit_cast(short8, u1);
        floatx4 cinit = {initv, initv, initv, initv};
        floatx4 acc = __builtin_amdgcn_mfma_f32_16x16x32_bf16(afrag[0], b0, cinit, 0, 0, 0);
        acc = __builtin_amdgcn_mfma_f32_16x16x32_bf16(afrag[1], b1, acc, 0, 0, 0);
        #pragma unroll
        for (int r = 0; r < 4; ++r) {
            unsigned pb = (__builtin_bit_cast(unsigned, acc[r]) & 0xFFFFFC00u) | idxv;
            best[r] = fmaxf(best[r], __builtin_bit_cast(float, pb));
        }
    }

    // ---- argmax across the 16 lanes sharing each C-row; C row = quad*4+r ----
    #pragma unroll
    for (int r = 0; r < 4; ++r) {
        float v = best[r];
        v = fmaxf(v, __shfl_xor(v, 1, 64));
        v = fmaxf(v, __shfl_xor(v, 2, 64));
        v = fmaxf(v, __shfl_xor(v, 4, 64));
        v = fmaxf(v, __shfl_xor(v, 8, 64));
        best[r] = v;
    }
    if (col == 0) {
        #pragma unroll
        for (int r = 0; r < 4; ++r)
            s_idx[wave * 16 + quad * 4 + r] =
                (int)(__builtin_bit_cast(unsigned, best[r]) & 1023u);
    }
    __syncthreads();   // s_idx is read cross-wave below

    // ---- epilogue: thread t -> point p0+(t&255), d-quarter t>>8.
    //      Stores/loads coalesce 1 KB per d-plane across 256 threads. ----
    {
        int n   = p0 + (tid & 255);
        int dq  = tid >> 8;
        int idx = s_idx[tid & 255];
        size_t base = ((size_t)(n >> 12) << 18) + (n & 4095);
        float* op = out + base;
        const float* xp = x + base;   // L2-hot: same 64 KB the block just read
        float lsum = 0.0f;
        #pragma unroll
        for (int j = 0; j < 4; ++j) {   // 4 x 8B LDS reads = 16 bf16
            unsigned long long u = *(const unsigned long long*)&s_cb[idx * ROWP + dq * 16 + j * 4];
            #pragma unroll
            for (int e = 0; e < 4; ++e) {
                int d = dq * 16 + j * 4 + e;
                float c = bf2f((short)(u >> (16 * e)));
                float xv = xp[(size_t)d * HW];
                op[(size_t)d * HW] = c;
                float diff = xv - c;
                lsum = fmaf(diff, diff, lsum);
            }
        }
        #pragma unroll
        for (int off = 32; off > 0; off >>= 1)
            lsum += __shfl_down(lsum, off, 64);
        if (lane == 0) s_red[wave] = lsum;
    }
    __syncthreads();
    if (tid == 0) {
        float s = 0.0f;
        #pragma unroll
        for (int w = 0; w < 16; ++w) s += s_red[w];
        atomicAdd(loss_ptr, s * (1.25f / (float)((size_t)NPTS * DIM)));
    }
}

extern "C" void kernel_launch(void* const* d_in, const int* in_sizes, int n_in,
                              void* d_out, int out_size, void* d_ws, size_t ws_size,
                              hipStream_t stream) {
    const float* x  = (const float*)d_in[0];   // [16,64,64,64] NCHW fp32
    const float* cb = (const float*)d_in[1];   // [1024,64] fp32
    float* out      = (float*)d_out;           // quantized (4194304) + loss (1)
    float* loss_ptr = out + (size_t)NPTS * DIM;

    vq_zero<<<1, 64, 0, stream>>>(loss_ptr);
    vq_main<<<NPTS / 256, 1024, 0, stream>>>(x, cb, out, loss_ptr);
}

// Round 4
// 90.490 us; speedup vs baseline: 8.2627x; 1.0259x over previous
//
#include <hip/hip_runtime.h>

#define NPTS   65536
#define DIM    64
#define KCODES 1024
#define HW     4096
#define ROWP   72          // padded LDS row stride (bf16 elems): 144 B, 16B-aligned

typedef __attribute__((ext_vector_type(8))) short  short8;
typedef __attribute__((ext_vector_type(4))) float  floatx4;

__device__ __forceinline__ short f2bf(float f) {   // RNE fp32 -> bf16
    unsigned u = __builtin_bit_cast(unsigned, f);
    u = (u + 0x7FFFu + ((u >> 16) & 1u)) >> 16;
    return (short)u;
}
__device__ __forceinline__ float bf2f(short s) {
    unsigned u = ((unsigned)(unsigned short)s) << 16;
    return __builtin_bit_cast(float, u);
}

// Prep (runs once per launch): fp32 codebook -> bf16 codebook in d_ws,
// plus -0.5*||c_bf16||^2 (fp32), plus zero the loss slot.
__global__ void vq_prep(const float* __restrict__ cb, short* __restrict__ cbbf,
                        float* __restrict__ cbn, float* __restrict__ loss_ptr) {
    int k = blockIdx.x * 256 + threadIdx.x;
    if (k == 0) *loss_ptr = 0.0f;
    if (k >= KCODES) return;
    const float* row = cb + (size_t)k * DIM;
    float ns = 0.0f;
    #pragma unroll
    for (int c = 0; c < 8; ++c) {          // 8 chunks of 8 elems
        short8 v;
        #pragma unroll
        for (int e = 0; e < 8; ++e) {
            short h = f2bf(row[c * 8 + e]);
            v[e] = h;
            float cf = bf2f(h);
            ns = fmaf(cf, cf, ns);
        }
        *(short8*)&cbbf[(size_t)k * DIM + c * 8] = v;   // 16B-aligned store
    }
    cbn[k] = -0.5f * ns;
}

__global__ __launch_bounds__(1024, 4) void vq_main(
    const float* __restrict__ x, const short* __restrict__ cbbf,
    const float* __restrict__ cbn, float* __restrict__ out,
    float* __restrict__ loss_ptr)
{
    __shared__ __align__(16) short s_cb[KCODES * ROWP];   // 144 KB bf16 codebook
    __shared__ float s_cbn[KCODES];                        // 4 KB
    __shared__ float s_part[4][256];                       // per-code-chunk best (packed)
    __shared__ float s_red[16];

    const int tid  = threadIdx.x;
    const int lane = tid & 63;
    const int wave = tid >> 6;
    const int col  = lane & 15;   // MFMA m/n index
    const int quad = lane >> 4;   // MFMA k-group / C-row-group
    const int pg   = wave & 3;    // point group: 64 points
    const int kc   = wave >> 2;   // code chunk: 256 codes

    // ---- stage bf16 codebook (pure copy, padded rows) + norms ----
    #pragma unroll
    for (int i = 0; i < 8; ++i) {
        int chunk = tid + 1024 * i;            // 8192 x 16B chunks
        short8 v = *(const short8*)(cbbf + (size_t)chunk * 8);
        int code = chunk >> 3, part = chunk & 7;
        *(short8*)&s_cb[code * ROWP + part * 8] = v;   // ds_write_b128, aligned
    }
    s_cbn[tid & 1023] = cbn[tid & 1023];

    // ---- A fragments: wave owns 64 points (4 tiles); A[m=col][k=quad*8+j] ----
    const int p0 = blockIdx.x * 256;
    short8 afrag[4][2];
    #pragma unroll
    for (int p = 0; p < 4; ++p) {
        int n = p0 + pg * 64 + p * 16 + col;
        const float* bp = x + ((size_t)(n >> 12) << 18) + (n & 4095);
        #pragma unroll
        for (int kh = 0; kh < 2; ++kh) {
            int dbase = kh * 32 + quad * 8;
            short8 f;
            #pragma unroll
            for (int j = 0; j < 8; ++j)
                f[j] = f2bf(bp[(size_t)(dbase + j) * HW]);
            afrag[p][kh] = f;
        }
    }
    __syncthreads();

    // ---- main loop: 16 tiles of 16 codes (this wave's 256-code chunk).
    //      argmax of (x.c - 0.5||c||^2), code idx packed in low 10 mantissa bits ----
    float best[4][4];
    #pragma unroll
    for (int p = 0; p < 4; ++p)
        #pragma unroll
        for (int r = 0; r < 4; ++r) best[p][r] = -3.4e38f;

    #pragma unroll 4
    for (int t = 0; t < 16; ++t) {
        const int code = kc * 256 + t * 16 + col;
        const float initv = s_cbn[code];
        const unsigned idxv = (unsigned)code;
        const short* rp = &s_cb[code * ROWP];
        const short8 b0 = *(const short8*)(rp + quad * 8);        // ds_read_b128
        const short8 b1 = *(const short8*)(rp + 32 + quad * 8);   // ds_read_b128
        floatx4 cinit = {initv, initv, initv, initv};
        #pragma unroll
        for (int p = 0; p < 4; ++p) {
            floatx4 acc = __builtin_amdgcn_mfma_f32_16x16x32_bf16(afrag[p][0], b0, cinit, 0, 0, 0);
            acc = __builtin_amdgcn_mfma_f32_16x16x32_bf16(afrag[p][1], b1, acc, 0, 0, 0);
            #pragma unroll
            for (int r = 0; r < 4; ++r) {
                unsigned pb = (__builtin_bit_cast(unsigned, acc[r]) & 0xFFFFFC00u) | idxv;
                best[p][r] = fmaxf(best[p][r], __builtin_bit_cast(float, pb));
            }
        }
    }

    // ---- reduce over the 16 cols sharing each C-row, then publish per-chunk best ----
    #pragma unroll
    for (int p = 0; p < 4; ++p)
        #pragma unroll
        for (int r = 0; r < 4; ++r) {
            float v = best[p][r];
            v = fmaxf(v, __shfl_xor(v, 1, 64));
            v = fmaxf(v, __shfl_xor(v, 2, 64));
            v = fmaxf(v, __shfl_xor(v, 4, 64));
            v = fmaxf(v, __shfl_xor(v, 8, 64));
            best[p][r] = v;
        }
    if (col == 0) {
        #pragma unroll
        for (int p = 0; p < 4; ++p)
            #pragma unroll
            for (int r = 0; r < 4; ++r)
                s_part[kc][pg * 64 + p * 16 + quad * 4 + r] = best[p][r];
    }
    __syncthreads();

    // ---- epilogue: thread t -> point p0+(t&255), d-quarter t>>8 ----
    {
        int pt = tid & 255;
        int dq = tid >> 8;
        float m = fmaxf(fmaxf(s_part[0][pt], s_part[1][pt]),
                        fmaxf(s_part[2][pt], s_part[3][pt]));
        int idx = (int)(__builtin_bit_cast(unsigned, m) & 1023u);

        int n = p0 + pt;
        size_t base = ((size_t)(n >> 12) << 18) + (n & 4095);
        float* op = out + base;
        const float* xp = x + base;   // L2-hot re-read
        float lsum = 0.0f;
        #pragma unroll
        for (int j = 0; j < 4; ++j) {   // 4 x 8B LDS reads = 16 bf16
            unsigned long long u = *(const unsigned long long*)&s_cb[idx * ROWP + dq * 16 + j * 4];
            #pragma unroll
            for (int e = 0; e < 4; ++e) {
                int d = dq * 16 + j * 4 + e;
                float c = bf2f((short)(u >> (16 * e)));
                float xv = xp[(size_t)d * HW];
                op[(size_t)d * HW] = c;
                float diff = xv - c;
                lsum = fmaf(diff, diff, lsum);
            }
        }
        #pragma unroll
        for (int off = 32; off > 0; off >>= 1)
            lsum += __shfl_down(lsum, off, 64);
        if (lane == 0) s_red[wave] = lsum;
    }
    __syncthreads();
    if (tid == 0) {
        float s = 0.0f;
        #pragma unroll
        for (int w = 0; w < 16; ++w) s += s_red[w];
        atomicAdd(loss_ptr, s * (1.25f / (float)((size_t)NPTS * DIM)));
    }
}

extern "C" void kernel_launch(void* const* d_in, const int* in_sizes, int n_in,
                              void* d_out, int out_size, void* d_ws, size_t ws_size,
                              hipStream_t stream) {
    const float* x  = (const float*)d_in[0];   // [16,64,64,64] NCHW fp32
    const float* cb = (const float*)d_in[1];   // [1024,64] fp32
    float* out      = (float*)d_out;           // quantized (4194304) + loss (1)
    float* loss_ptr = out + (size_t)NPTS * DIM;

    short* cbbf = (short*)d_ws;                        // 128 KB bf16 codebook
    float* cbn  = (float*)((char*)d_ws + KCODES * DIM * sizeof(short));  // 4 KB norms

    vq_prep<<<KCODES / 256, 256, 0, stream>>>(cb, cbbf, cbn, loss_ptr);
    vq_main<<<NPTS / 256, 1024, 0, stream>>>(x, cbbf, cbn, out, loss_ptr);
}